// Round 3
// baseline (495.915 us; speedup 1.0000x reference)
//
#include <hip/hip_runtime.h>
#include <hip/hip_bf16.h>
#include <math.h>

#define DEV __device__ __forceinline__

constexpr int B=8, C=64, DIM=256, HID=128, S=64, NH=16, HD=4, LPIX=784;

// workspace offsets in floats
constexpr size_t OFF_X1O = 0;                                   // B*C*L
constexpr size_t OFF_T1  = OFF_X1O + (size_t)B*C*LPIX;          // B*HID*L
constexpr size_t OFF_T2  = OFF_T1  + (size_t)B*HID*LPIX;        // B*C*L
constexpr size_t OFF_XA  = OFF_T2  + (size_t)B*C*LPIX;          // B*DIM*L
constexpr size_t OFF_MP  = OFF_XA  + (size_t)B*DIM*LPIX;        // B*C*L
constexpr size_t OFF_XT  = OFF_MP  + (size_t)B*C*LPIX;          // B*C*100
constexpr size_t OFF_ATT = OFF_XT  + (size_t)B*C*100;           // B*C*100
constexpr size_t OFF_BC1 = OFF_ATT + (size_t)B*C*100;           // B*192*L
constexpr size_t OFF_BC2 = OFF_BC1 + (size_t)B*192*LPIX;        // B*192*L
constexpr size_t OFF_WGT = OFF_BC2 + (size_t)B*192*LPIX;        // B*S*L
constexpr size_t OFF_H   = OFF_WGT + (size_t)B*S*LPIX;          // B*C*S
constexpr size_t OFF_G1  = OFF_H   + (size_t)B*C*S;             // B*C*S
constexpr size_t OFF_HO  = OFF_G1  + (size_t)B*C*S;             // B*C*S
constexpr size_t OFF_QKV = OFF_HO  + (size_t)B*C*S;             // 3*B*NH*L*HD
constexpr size_t OFF_O   = OFF_QKV + (size_t)3*B*NH*LPIX*HD;    // B*L*C
constexpr size_t OFF_MID = OFF_O   + (size_t)B*LPIX*C;          // B*HID*L

DEV float bnorm(float x, const float* p, int c, int nc){
  float g=p[c], bb=p[nc+c], m=p[2*nc+c], v=p[3*nc+c];
  return (x-m)*(g*rsqrtf(v+1e-5f))+bb;
}

// ---- branch 1 ----
__global__ void k_dw1(const float* X, const float* w, const float* bias, const float* bnp, float* out){
  int idx = blockIdx.x*256+threadIdx.x; if(idx>=B*C*LPIX) return;
  int l=idx%LPIX, c=(idx/LPIX)%C, b=idx/(LPIX*C);
  int y=l/28, x=l%28;
  const float* xp = X + ((size_t)(b*DIM+c))*LPIX;
  float s = bias[c];
  for(int ky=0;ky<7;ky++){ int iy=y+ky-3; if(iy<0||iy>=28) continue;
    for(int kx=0;kx<7;kx++){ int ix=x+kx-3; if(ix<0||ix>=28) continue;
      s += xp[(size_t)iy*28+ix]*w[(size_t)c*49+ky*7+kx]; } }
  out[idx] = bnorm(s,bnp,c,C);
}

__global__ void k_star(const float* x1o, const float* f1w,const float* f1b,const float* f2w,const float* f2b,float* t1){
  int idx = blockIdx.x*256+threadIdx.x; if(idx>=B*HID*LPIX) return;
  int l=idx%LPIX, j=(idx/LPIX)%HID, b=idx/(LPIX*HID);
  const float* xp = x1o + (size_t)b*C*LPIX + l;
  float a=f1b[j], g=f2b[j];
  for(int c=0;c<C;c++){ float xv=xp[(size_t)c*LPIX]; a+=f1w[(size_t)j*C+c]*xv; g+=f2w[(size_t)j*C+c]*xv; }
  a = fminf(fmaxf(a,0.f),6.f);
  t1[idx]=a*g;
}

__global__ void k_gproj(const float* t1, const float* gw,const float* gb,const float* bnp,float* t2){
  int idx = blockIdx.x*256+threadIdx.x; if(idx>=B*C*LPIX) return;
  int l=idx%LPIX, c=(idx/LPIX)%C, b=idx/(LPIX*C);
  const float* tp = t1 + (size_t)b*HID*LPIX + l;
  float s=gb[c];
  for(int j=0;j<HID;j++) s+=gw[(size_t)c*HID+j]*tp[(size_t)j*LPIX];
  t2[idx]=bnorm(s,bnp,c,C);
}

__global__ void k_dw2(const float* t2,const float* w,const float* bias,float* xa){
  int idx = blockIdx.x*256+threadIdx.x; if(idx>=B*C*LPIX) return;
  int l=idx%LPIX, c=(idx/LPIX)%C, b=idx/(LPIX*C);
  int y=l/28, x=l%28;
  const float* tp = t2 + ((size_t)(b*C+c))*LPIX;
  float s=bias[c];
  for(int ky=0;ky<7;ky++){ int iy=y+ky-3; if(iy<0||iy>=28) continue;
    for(int kx=0;kx<7;kx++){ int ix=x+kx-3; if(ix<0||ix>=28) continue;
      s += tp[(size_t)iy*28+ix]*w[(size_t)c*49+ky*7+kx]; } }
  xa[((size_t)(b*DIM+c))*LPIX + l] = s;
}

// ---- branch 2 ----
__global__ void k_mp(const float* X, float* mp){
  int idx = blockIdx.x*256+threadIdx.x; if(idx>=B*C*LPIX) return;
  int l=idx%LPIX, c=(idx/LPIX)%C, b=idx/(LPIX*C);
  int y=l/28, x=l%28;
  const float* xp = X + ((size_t)(b*DIM+64+c))*LPIX;
  float m=-1e30f;
  for(int dy=-1;dy<=1;dy++){ int iy=y+dy; if(iy<0||iy>=28) continue;
    for(int dx=-1;dx<=1;dx++){ int ix=x+dx; if(ix<0||ix>=28) continue;
      m=fmaxf(m,xp[(size_t)iy*28+ix]); } }
  mp[idx]=m;
}

DEV int refl(int p){ int k=p-1; if(k<0)k=-k; if(k>27)k=54-k; return k; }

__global__ void k_blur(const float* mp, float* xt){
  int idx = blockIdx.x*256+threadIdx.x; if(idx>=B*C*100) return;
  int j=idx%10, i=(idx/10)%10, c=(idx/100)%C, b=idx/(100*C);
  const float* p = mp + ((size_t)(b*C+c))*LPIX;
  const float fw[4]={0.125f,0.375f,0.375f,0.125f};
  float s=0;
  for(int ky=0;ky<4;ky++){ int rr=refl(3*i+ky);
    for(int kx=0;kx<4;kx++){ int cc=refl(3*j+kx);
      s += fw[ky]*fw[kx]*p[(size_t)rr*28+cc]; } }
  xt[idx]=s;
}

__global__ void k_mra(const float* xt, const float* h1w,const float* v1w,const float* h2w,const float* v2w,const float* bnp,float* att){
  int idx = blockIdx.x*256+threadIdx.x; if(idx>=B*C*100) return;
  int j=idx%10, r=(idx/10)%10, c=(idx/100)%C, b=idx/(100*C);
  const float* xp = xt + (size_t)(b*C+c)*100;
  float s=0;
  // xh1: kernel (11,3), pad (5,1)
  for(int kh=0;kh<11;kh++){ int a=r+kh-5; if(a<0||a>=10) continue;
    for(int kw=0;kw<3;kw++){ int b2=j+kw-1; if(b2<0||b2>=10) continue;
      s+=xp[a*10+b2]*h1w[(size_t)c*33+kh*3+kw]; } }
  // xw1: kernel (3,11), pad (1,5)
  for(int kh=0;kh<3;kh++){ int a=r+kh-1; if(a<0||a>=10) continue;
    for(int kw=0;kw<11;kw++){ int b2=j+kw-5; if(b2<0||b2>=10) continue;
      s+=xp[a*10+b2]*v1w[(size_t)c*33+kh*11+kw]; } }
  // xh2: conv (11,3) pad (5,1) on h_transform(xt) (10x19), then inv_h at (r,j)
  { int t=20*r+j; int r2=t/19, j2=t%19;
    for(int kh=0;kh<11;kh++){ int a=r2+kh-5; if(a<0||a>=10) continue;
      for(int kw=0;kw<3;kw++){ int b2=j2+kw-1; if(b2<0||b2>=19) continue;
        int i2=19*a+b2; int row=i2/20, col=i2%20;
        if(col<10) s+=xp[row*10+col]*h2w[(size_t)c*33+kh*3+kw]; } } }
  // xw2: conv (3,11) pad (1,5) on v_transform(xt) (19x10), then inv_v at (r,j)
  { int t=20*j+r; int p=t%19, q=t/19;
    for(int kh=0;kh<3;kh++){ int a=p+kh-1; if(a<0||a>=19) continue;
      for(int kw=0;kw<11;kw++){ int b2=q+kw-5; if(b2<0||b2>=10) continue;
        int i2=19*b2+a; int row=i2/20, col=i2%20;
        if(col<10) s+=xp[col*10+row]*v2w[(size_t)c*33+kh*11+kw]; } } }
  s = bnorm(s,bnp,c,C);
  att[idx] = 1.f/(1.f+__expf(-s));
}

__global__ void k_x2(const float* X, const float* att, float* xa){
  int idx = blockIdx.x*256+threadIdx.x; if(idx>=B*C*LPIX) return;
  int l=idx%LPIX, c=(idx/LPIX)%C, b=idx/(LPIX*C);
  int y=l/28, x=l%28;
  int ri=(y*10)/28, ci=(x*10)/28;
  float a = att[(size_t)(b*C+c)*100 + ri*10+ci];
  size_t xi = ((size_t)(b*DIM+64+c))*LPIX + l;
  xa[xi] = X[xi]*a;
}

// ---- branch 3 ----
__global__ void k_bcdt(const float* X, const float* w, float* bc1){
  int idx = blockIdx.x*256+threadIdx.x; if(idx>=B*192*LPIX) return;
  int l=idx%LPIX, o=(idx/LPIX)%192, b=idx/(LPIX*192);
  const float* xp = X + ((size_t)(b*DIM+128))*LPIX + l;
  float s=0;
  for(int c=0;c<C;c++) s+=w[(size_t)o*C+c]*xp[(size_t)c*LPIX];
  bc1[idx]=s;
}

__global__ void k_ssddw(const float* bc1, const float* w, float* bc2){
  int idx = blockIdx.x*256+threadIdx.x; if(idx>=B*192*LPIX) return;
  int l=idx%LPIX, ch=(idx/LPIX)%192, b=idx/(LPIX*192);
  int y=l/28, x=l%28;
  const float* p = bc1 + (size_t)(b*192+ch)*LPIX;
  float s=0;
  for(int ky=0;ky<3;ky++){ int iy=y+ky-1; if(iy<0||iy>=28) continue;
    for(int kx=0;kx<3;kx++){ int ix=x+kx-1; if(ix<0||ix>=28) continue;
      s += p[(size_t)iy*28+ix]*w[(size_t)ch*9+ky*3+kx]; } }
  bc2[idx]=s;
}

// softmax over L of dt (A_param shift is softmax-invariant), times Bm
__global__ void k_ssd_softmax(const float* bc2, float* wgt){
  int bs = blockIdx.x; int b=bs>>6, s_=bs&63;
  const float* dt = bc2 + ((size_t)(b*192+128+s_))*LPIX;
  const float* Bm = bc2 + ((size_t)(b*192+s_))*LPIX;
  __shared__ float row[LPIX];
  __shared__ float red[256];
  int t=threadIdx.x;
  float mx=-1e30f;
  for(int l=t;l<LPIX;l+=256){ float v=dt[l]; row[l]=v; mx=fmaxf(mx,v); }
  red[t]=mx; __syncthreads();
  for(int o=128;o>0;o>>=1){ if(t<o) red[t]=fmaxf(red[t],red[t+o]); __syncthreads(); }
  mx=red[0]; __syncthreads();
  float sum=0;
  for(int l=t;l<LPIX;l+=256){ float e=__expf(row[l]-mx); row[l]=e; sum+=e; }
  red[t]=sum; __syncthreads();
  for(int o=128;o>0;o>>=1){ if(t<o) red[t]+=red[t+o]; __syncthreads(); }
  float inv=1.f/red[0];
  for(int l=t;l<LPIX;l+=256) wgt[((size_t)(b*S+s_))*LPIX+l] = row[l]*inv*Bm[l];
}

__global__ void k_h(const float* X, const float* wgt, float* h){
  int idx = blockIdx.x*256+threadIdx.x; if(idx>=B*C*S) return;
  int s_=idx%S, c=(idx/S)%C, b=idx/(S*C);
  const float* xp = X + ((size_t)(b*DIM+128+c))*LPIX;
  const float* wp = wgt + (size_t)(b*S+s_)*LPIX;
  float acc=0;
  for(int l=0;l<LPIX;l++) acc += xp[l]*wp[l];
  h[idx]=acc;
}

__global__ void k_mix(const float* h, const float* hzw, const float* Dp, float* g1){
  int idx = blockIdx.x*256+threadIdx.x; if(idx>=B*C*S) return;
  int s_=idx%S, c=(idx/S)%C, b=idx/(S*C);
  const float* hp = h + (size_t)b*C*S + s_;
  float hv=0, zv=0;
  for(int k=0;k<C;k++){ float x=hp[(size_t)k*S]; hv+=hzw[(size_t)c*C+k]*x; zv+=hzw[(size_t)(C+c)*C+k]*x; }
  float sil = zv/(1.f+__expf(-zv));
  g1[idx] = hv*sil + hv*Dp[0];
}

__global__ void k_ho(const float* g1, const float* outw, float* ho){
  int idx = blockIdx.x*256+threadIdx.x; if(idx>=B*C*S) return;
  int s_=idx%S, c=(idx/S)%C, b=idx/(S*C);
  float acc=0;
  for(int k=0;k<C;k++) acc += outw[(size_t)c*C+k]*g1[((size_t)(b*C+k))*S+s_];
  ho[idx]=acc;
}

__global__ void k_x3(const float* ho, const float* bc2, float* xa){
  int idx = blockIdx.x*256+threadIdx.x; if(idx>=B*C*LPIX) return;
  int l=idx%LPIX, c=(idx/LPIX)%C, b=idx/(LPIX*C);
  const float* hp = ho + (size_t)(b*C+c)*S;
  const float* cm = bc2 + ((size_t)(b*192+64))*LPIX + l;
  float acc=0;
  for(int s_=0;s_<S;s_++) acc += hp[s_]*cm[(size_t)s_*LPIX];
  xa[((size_t)(b*DIM+128+c))*LPIX + l] = acc;
}

// ---- branch 4 ----
__global__ void k_qkv(const float* X, const float* w, float* qkvb){
  int idx = blockIdx.x*256+threadIdx.x; if(idx>=B*192*LPIX) return;
  int l=idx%LPIX, o=(idx/LPIX)%192, b=idx/(LPIX*192);
  const float* xp = X + ((size_t)(b*DIM+192))*LPIX + l;
  float s=0;
  for(int c=0;c<C;c++) s += w[(size_t)o*C+c]*xp[(size_t)c*LPIX];
  int which=o>>6, rem=o&63, head=rem>>2, d=rem&3;
  qkvb[(size_t)which*B*NH*LPIX*HD + ((size_t)(b*NH+head)*LPIX+l)*HD + d] = s;
}

__global__ void k_attn(const float* qkvb, float* obuf){
  int bh = blockIdx.x>>2, quad = blockIdx.x&3;
  int b = bh>>4, h = bh&15;
  const float* q = qkvb + (size_t)bh*LPIX*HD;
  const float* k = qkvb + (size_t)B*NH*LPIX*HD   + (size_t)bh*LPIX*HD;
  const float* v = qkvb + (size_t)2*B*NH*LPIX*HD + (size_t)bh*LPIX*HD;
  __shared__ float ks[LPIX*HD], vs[LPIX*HD];
  for(int i=threadIdx.x;i<LPIX*HD;i+=256){ ks[i]=k[i]; vs[i]=v[i]; }
  __syncthreads();
  int l0=quad*196, l1=l0+196;
  for(int l=l0+threadIdx.x; l<l1; l+=256){
    float q0=q[l*4],q1=q[l*4+1],q2=q[l*4+2],q3=q[l*4+3];
    float mx=-1e30f, ls=0, a0=0,a1=0,a2=0,a3=0;
    for(int m=0;m<LPIX;m++){
      float sc=0.5f*(q0*ks[m*4]+q1*ks[m*4+1]+q2*ks[m*4+2]+q3*ks[m*4+3]);
      float p;
      if(sc>mx){ float r=__expf(mx-sc); a0*=r;a1*=r;a2*=r;a3*=r; ls*=r; mx=sc; p=1.f; }
      else p=__expf(sc-mx);
      ls+=p; a0+=p*vs[m*4]; a1+=p*vs[m*4+1]; a2+=p*vs[m*4+2]; a3+=p*vs[m*4+3];
    }
    float inv=1.f/ls;
    float* op = obuf + ((size_t)(b*LPIX+l))*C + h*4;
    op[0]=a0*inv; op[1]=a1*inv; op[2]=a2*inv; op[3]=a3*inv;
  }
}

__global__ void k_x4(const float* X, const float* obuf, const float* projw, const float* bnp, float* xa){
  int idx = blockIdx.x*256+threadIdx.x; if(idx>=B*C*LPIX) return;
  int l=idx%LPIX, c=(idx/LPIX)%C, b=idx/(LPIX*C);
  const float* op = obuf + ((size_t)(b*LPIX+l))*C;
  float s=0;
  for(int k=0;k<C;k++) s += projw[(size_t)c*C+k]*op[k];
  s += X[((size_t)(b*DIM+192+c))*LPIX + l];
  xa[((size_t)(b*DIM+192+c))*LPIX + l] = bnorm(s,bnp,c,C);
}

// ---- merge MLP ----
__global__ void k_mid(const float* xa, const float* m1w, const float* bnp, float* mid){
  int idx = blockIdx.x*256+threadIdx.x; if(idx>=B*HID*LPIX) return;
  int l=idx%LPIX, j=(idx/LPIX)%HID, b=idx/(LPIX*HID);
  const float* xp = xa + (size_t)b*DIM*LPIX + l;
  float s=0;
  for(int c=0;c<DIM;c++) s += m1w[(size_t)j*DIM+c]*xp[(size_t)c*LPIX];
  s = bnorm(s,bnp,j,HID);
  mid[idx] = fmaxf(s,0.f);
}

__global__ void k_out(const float* X, const float* mid, const float* m2w, const float* bnp, float* out){
  int idx = blockIdx.x*256+threadIdx.x; if(idx>=B*DIM*LPIX) return;
  int l=idx%LPIX, c=(idx/LPIX)%DIM, b=idx/(LPIX*DIM);
  const float* mp_ = mid + (size_t)b*HID*LPIX + l;
  float s=0;
  for(int j=0;j<HID;j++) s += m2w[(size_t)c*HID+j]*mp_[(size_t)j*LPIX];
  s = bnorm(s,bnp,c,DIM);
  out[idx] = s + X[idx];   // fp32 output — reference returns float32
}

extern "C" void kernel_launch(void* const* d_in, const int* in_sizes, int n_in,
                              void* d_out, int out_size, void* d_ws, size_t ws_size,
                              hipStream_t stream) {
  const float* X      = (const float*)d_in[0];
  const float* dw1_w  = (const float*)d_in[1];
  const float* dw1_b  = (const float*)d_in[2];
  const float* bn_dw1 = (const float*)d_in[3];
  const float* f1_w   = (const float*)d_in[4];
  const float* f1_b   = (const float*)d_in[5];
  const float* f2_w   = (const float*)d_in[6];
  const float* f2_b   = (const float*)d_in[7];
  const float* g_w    = (const float*)d_in[8];
  const float* g_b    = (const float*)d_in[9];
  const float* bn_g   = (const float*)d_in[10];
  const float* dw2_w  = (const float*)d_in[11];
  const float* dw2_b  = (const float*)d_in[12];
  const float* hatt1w = (const float*)d_in[13];
  const float* vatt1w = (const float*)d_in[14];
  const float* hatt2w = (const float*)d_in[15];
  const float* vatt2w = (const float*)d_in[16];
  const float* bn_mra = (const float*)d_in[17];
  const float* bcdt_w = (const float*)d_in[18];
  const float* ssd_dw = (const float*)d_in[19];
  const float* hz_w   = (const float*)d_in[20];
  const float* out_w  = (const float*)d_in[21];
  // d_in[22] = A_param: softmax over L is invariant to a per-(b,s) constant shift -> unused
  const float* D_p    = (const float*)d_in[23];
  const float* qkv_w  = (const float*)d_in[24];
  const float* proj_w = (const float*)d_in[25];
  const float* bn_n4  = (const float*)d_in[26];
  const float* mlp1_w = (const float*)d_in[27];
  const float* bn_mlp = (const float*)d_in[28];
  const float* mlp2_w = (const float*)d_in[29];
  const float* bn_n1  = (const float*)d_in[30];

  float* ws   = (float*)d_ws;
  float* x1o  = ws+OFF_X1O;  float* t1  = ws+OFF_T1;  float* t2  = ws+OFF_T2;
  float* xa   = ws+OFF_XA;   float* mpb = ws+OFF_MP;  float* xt  = ws+OFF_XT;
  float* att  = ws+OFF_ATT;  float* bc1 = ws+OFF_BC1; float* bc2 = ws+OFF_BC2;
  float* wgt  = ws+OFF_WGT;  float* hbuf= ws+OFF_H;   float* g1  = ws+OFF_G1;
  float* ho   = ws+OFF_HO;   float* qkvb= ws+OFF_QKV; float* obuf= ws+OFF_O;
  float* mid  = ws+OFF_MID;

  dim3 blk(256);
  #define NB(n) dim3((unsigned)(((n)+255)/256))
  const int NCL = B*C*LPIX;

  // branch 1
  k_dw1  <<<NB(NCL),blk,0,stream>>>(X,dw1_w,dw1_b,bn_dw1,x1o);
  k_star <<<NB(B*HID*LPIX),blk,0,stream>>>(x1o,f1_w,f1_b,f2_w,f2_b,t1);
  k_gproj<<<NB(NCL),blk,0,stream>>>(t1,g_w,g_b,bn_g,t2);
  k_dw2  <<<NB(NCL),blk,0,stream>>>(t2,dw2_w,dw2_b,xa);
  // branch 2
  k_mp   <<<NB(NCL),blk,0,stream>>>(X,mpb);
  k_blur <<<NB(B*C*100),blk,0,stream>>>(mpb,xt);
  k_mra  <<<NB(B*C*100),blk,0,stream>>>(xt,hatt1w,vatt1w,hatt2w,vatt2w,bn_mra,att);
  k_x2   <<<NB(NCL),blk,0,stream>>>(X,att,xa);
  // branch 3
  k_bcdt <<<NB(B*192*LPIX),blk,0,stream>>>(X,bcdt_w,bc1);
  k_ssddw<<<NB(B*192*LPIX),blk,0,stream>>>(bc1,ssd_dw,bc2);
  k_ssd_softmax<<<dim3(B*S),blk,0,stream>>>(bc2,wgt);
  k_h    <<<NB(B*C*S),blk,0,stream>>>(X,wgt,hbuf);
  k_mix  <<<NB(B*C*S),blk,0,stream>>>(hbuf,hz_w,D_p,g1);
  k_ho   <<<NB(B*C*S),blk,0,stream>>>(g1,out_w,ho);
  k_x3   <<<NB(NCL),blk,0,stream>>>(ho,bc2,xa);
  // branch 4
  k_qkv  <<<NB(B*192*LPIX),blk,0,stream>>>(X,qkv_w,qkvb);
  k_attn <<<dim3(B*NH*4),blk,0,stream>>>(qkvb,obuf);
  k_x4   <<<NB(NCL),blk,0,stream>>>(X,obuf,proj_w,bn_n4,xa);
  // merge MLP
  k_mid  <<<NB(B*HID*LPIX),blk,0,stream>>>(xa,mlp1_w,bn_mlp,mid);
  k_out  <<<NB(B*DIM*LPIX),blk,0,stream>>>(X,mid,mlp2_w,bn_n1,(float*)d_out);
  #undef NB
}

// Round 4
// 442.539 us; speedup vs baseline: 1.1206x; 1.1206x over previous
//
#include <hip/hip_runtime.h>
#include <hip/hip_bf16.h>
#include <math.h>

#define DEV __device__ __forceinline__

constexpr int B=8, C=64, DIM=256, HID=128, S=64, NH=16, HD=4, LPIX=784;

// workspace offsets in floats
constexpr size_t OFF_X1O = 0;                                   // B*C*L
constexpr size_t OFF_T1  = OFF_X1O + (size_t)B*C*LPIX;          // B*HID*L
constexpr size_t OFF_T2  = OFF_T1  + (size_t)B*HID*LPIX;        // B*C*L
constexpr size_t OFF_XA  = OFF_T2  + (size_t)B*C*LPIX;          // B*DIM*L
constexpr size_t OFF_MP  = OFF_XA  + (size_t)B*DIM*LPIX;        // B*C*L
constexpr size_t OFF_XT  = OFF_MP  + (size_t)B*C*LPIX;          // B*C*100
constexpr size_t OFF_ATT = OFF_XT  + (size_t)B*C*100;           // B*C*100
constexpr size_t OFF_BC1 = OFF_ATT + (size_t)B*C*100;           // B*192*L
constexpr size_t OFF_BC2 = OFF_BC1 + (size_t)B*192*LPIX;        // B*192*L
constexpr size_t OFF_WGT = OFF_BC2 + (size_t)B*192*LPIX;        // B*S*L
constexpr size_t OFF_H   = OFF_WGT + (size_t)B*S*LPIX;          // B*C*S
constexpr size_t OFF_G1  = OFF_H   + (size_t)B*C*S;             // B*C*S
constexpr size_t OFF_HO  = OFF_G1  + (size_t)B*C*S;             // B*C*S
constexpr size_t OFF_QKV = OFF_HO  + (size_t)B*C*S;             // 3*B*NH*L*HD
constexpr size_t OFF_O   = OFF_QKV + (size_t)3*B*NH*LPIX*HD;    // B*L*C
constexpr size_t OFF_MID = OFF_O   + (size_t)B*LPIX*C;          // B*HID*L

DEV float bnorm(float x, const float* p, int c, int nc){
  float g=p[c], bb=p[nc+c], m=p[2*nc+c], v=p[3*nc+c];
  return (x-m)*(g*rsqrtf(v+1e-5f))+bb;
}

// ---- branch 1 ----
__global__ void k_dw1(const float* X, const float* w, const float* bias, const float* bnp, float* out){
  int idx = blockIdx.x*256+threadIdx.x; if(idx>=B*C*LPIX) return;
  int l=idx%LPIX, c=(idx/LPIX)%C, b=idx/(LPIX*C);
  int y=l/28, x=l%28;
  const float* xp = X + ((size_t)(b*DIM+c))*LPIX;
  float s = bias[c];
  for(int ky=0;ky<7;ky++){ int iy=y+ky-3; if(iy<0||iy>=28) continue;
    for(int kx=0;kx<7;kx++){ int ix=x+kx-3; if(ix<0||ix>=28) continue;
      s += xp[(size_t)iy*28+ix]*w[(size_t)c*49+ky*7+kx]; } }
  out[idx] = bnorm(s,bnp,c,C);
}

// 4 j-outputs per thread, 8 FMA per x-load
__global__ void k_star(const float* x1o, const float* f1w,const float* f1b,const float* f2w,const float* f2b,float* t1){
  int idx = blockIdx.x*256+threadIdx.x; if(idx>=B*(HID/4)*LPIX) return;
  int l=idx%LPIX, jg=(idx/LPIX)%(HID/4), b=idx/(LPIX*(HID/4));
  int j0=jg*4;
  const float* xp = x1o + (size_t)b*C*LPIX + l;
  float a[4], g[4];
  for(int t=0;t<4;t++){ a[t]=f1b[j0+t]; g[t]=f2b[j0+t]; }
  for(int c=0;c<C;c++){
    float xv = xp[(size_t)c*LPIX];
    for(int t=0;t<4;t++){ a[t]+=f1w[(size_t)(j0+t)*C+c]*xv; g[t]+=f2w[(size_t)(j0+t)*C+c]*xv; }
  }
  for(int t=0;t<4;t++){
    float av = fminf(fmaxf(a[t],0.f),6.f);
    t1[((size_t)(b*HID+j0+t))*LPIX + l] = av*g[t];
  }
}

__global__ void k_gproj(const float* t1, const float* gw,const float* gb,const float* bnp,float* t2){
  int idx = blockIdx.x*256+threadIdx.x; if(idx>=B*(C/4)*LPIX) return;
  int l=idx%LPIX, cg=(idx/LPIX)%(C/4), b=idx/(LPIX*(C/4));
  int c0=cg*4;
  const float* tp = t1 + (size_t)b*HID*LPIX + l;
  float s[4]; for(int t=0;t<4;t++) s[t]=gb[c0+t];
  for(int j=0;j<HID;j++){
    float xv = tp[(size_t)j*LPIX];
    for(int t=0;t<4;t++) s[t]+=gw[(size_t)(c0+t)*HID+j]*xv;
  }
  for(int t=0;t<4;t++) t2[((size_t)(b*C+c0+t))*LPIX + l]=bnorm(s[t],bnp,c0+t,C);
}

__global__ void k_dw2(const float* t2,const float* w,const float* bias,float* xa){
  int idx = blockIdx.x*256+threadIdx.x; if(idx>=B*C*LPIX) return;
  int l=idx%LPIX, c=(idx/LPIX)%C, b=idx/(LPIX*C);
  int y=l/28, x=l%28;
  const float* tp = t2 + ((size_t)(b*C+c))*LPIX;
  float s=bias[c];
  for(int ky=0;ky<7;ky++){ int iy=y+ky-3; if(iy<0||iy>=28) continue;
    for(int kx=0;kx<7;kx++){ int ix=x+kx-3; if(ix<0||ix>=28) continue;
      s += tp[(size_t)iy*28+ix]*w[(size_t)c*49+ky*7+kx]; } }
  xa[((size_t)(b*DIM+c))*LPIX + l] = s;
}

// ---- branch 2 ----
__global__ void k_mp(const float* X, float* mp){
  int idx = blockIdx.x*256+threadIdx.x; if(idx>=B*C*LPIX) return;
  int l=idx%LPIX, c=(idx/LPIX)%C, b=idx/(LPIX*C);
  int y=l/28, x=l%28;
  const float* xp = X + ((size_t)(b*DIM+64+c))*LPIX;
  float m=-1e30f;
  for(int dy=-1;dy<=1;dy++){ int iy=y+dy; if(iy<0||iy>=28) continue;
    for(int dx=-1;dx<=1;dx++){ int ix=x+dx; if(ix<0||ix>=28) continue;
      m=fmaxf(m,xp[(size_t)iy*28+ix]); } }
  mp[idx]=m;
}

DEV int refl(int p){ int k=p-1; if(k<0)k=-k; if(k>27)k=54-k; return k; }

__global__ void k_blur(const float* mp, float* xt){
  int idx = blockIdx.x*256+threadIdx.x; if(idx>=B*C*100) return;
  int j=idx%10, i=(idx/10)%10, c=(idx/100)%C, b=idx/(100*C);
  const float* p = mp + ((size_t)(b*C+c))*LPIX;
  const float fw[4]={0.125f,0.375f,0.375f,0.125f};
  float s=0;
  for(int ky=0;ky<4;ky++){ int rr=refl(3*i+ky);
    for(int kx=0;kx<4;kx++){ int cc=refl(3*j+kx);
      s += fw[ky]*fw[kx]*p[(size_t)rr*28+cc]; } }
  xt[idx]=s;
}

__global__ void k_mra(const float* xt, const float* h1w,const float* v1w,const float* h2w,const float* v2w,const float* bnp,float* att){
  int idx = blockIdx.x*256+threadIdx.x; if(idx>=B*C*100) return;
  int j=idx%10, r=(idx/10)%10, c=(idx/100)%C, b=idx/(100*C);
  const float* xp = xt + (size_t)(b*C+c)*100;
  float s=0;
  for(int kh=0;kh<11;kh++){ int a=r+kh-5; if(a<0||a>=10) continue;
    for(int kw=0;kw<3;kw++){ int b2=j+kw-1; if(b2<0||b2>=10) continue;
      s+=xp[a*10+b2]*h1w[(size_t)c*33+kh*3+kw]; } }
  for(int kh=0;kh<3;kh++){ int a=r+kh-1; if(a<0||a>=10) continue;
    for(int kw=0;kw<11;kw++){ int b2=j+kw-5; if(b2<0||b2>=10) continue;
      s+=xp[a*10+b2]*v1w[(size_t)c*33+kh*11+kw]; } }
  { int t=20*r+j; int r2=t/19, j2=t%19;
    for(int kh=0;kh<11;kh++){ int a=r2+kh-5; if(a<0||a>=10) continue;
      for(int kw=0;kw<3;kw++){ int b2=j2+kw-1; if(b2<0||b2>=19) continue;
        int i2=19*a+b2; int row=i2/20, col=i2%20;
        if(col<10) s+=xp[row*10+col]*h2w[(size_t)c*33+kh*3+kw]; } } }
  { int t=20*j+r; int p=t%19, q=t/19;
    for(int kh=0;kh<3;kh++){ int a=p+kh-1; if(a<0||a>=19) continue;
      for(int kw=0;kw<11;kw++){ int b2=q+kw-5; if(b2<0||b2>=10) continue;
        int i2=19*b2+a; int row=i2/20, col=i2%20;
        if(col<10) s+=xp[col*10+row]*v2w[(size_t)c*33+kh*11+kw]; } } }
  s = bnorm(s,bnp,c,C);
  att[idx] = 1.f/(1.f+__expf(-s));
}

__global__ void k_x2(const float* X, const float* att, float* xa){
  int idx = blockIdx.x*256+threadIdx.x; if(idx>=B*C*LPIX) return;
  int l=idx%LPIX, c=(idx/LPIX)%C, b=idx/(LPIX*C);
  int y=l/28, x=l%28;
  int ri=(y*10)/28, ci=(x*10)/28;
  float a = att[(size_t)(b*C+c)*100 + ri*10+ci];
  size_t xi = ((size_t)(b*DIM+64+c))*LPIX + l;
  xa[xi] = X[xi]*a;
}

// ---- branch 3 ----
__global__ void k_bcdt(const float* X, const float* w, float* bc1){
  int idx = blockIdx.x*256+threadIdx.x; if(idx>=B*48*LPIX) return;
  int l=idx%LPIX, og=(idx/LPIX)%48, b=idx/(LPIX*48);
  int o0=og*4;
  const float* xp = X + ((size_t)(b*DIM+128))*LPIX + l;
  float s[4]={0,0,0,0};
  for(int c=0;c<C;c++){ float xv=xp[(size_t)c*LPIX];
    for(int t=0;t<4;t++) s[t]+=w[(size_t)(o0+t)*C+c]*xv; }
  for(int t=0;t<4;t++) bc1[((size_t)(b*192+o0+t))*LPIX+l]=s[t];
}

__global__ void k_ssddw(const float* bc1, const float* w, float* bc2){
  int idx = blockIdx.x*256+threadIdx.x; if(idx>=B*192*LPIX) return;
  int l=idx%LPIX, ch=(idx/LPIX)%192, b=idx/(LPIX*192);
  int y=l/28, x=l%28;
  const float* p = bc1 + (size_t)(b*192+ch)*LPIX;
  float s=0;
  for(int ky=0;ky<3;ky++){ int iy=y+ky-1; if(iy<0||iy>=28) continue;
    for(int kx=0;kx<3;kx++){ int ix=x+kx-1; if(ix<0||ix>=28) continue;
      s += p[(size_t)iy*28+ix]*w[(size_t)ch*9+ky*3+kx]; } }
  bc2[idx]=s;
}

__global__ void k_ssd_softmax(const float* bc2, float* wgt){
  int bs = blockIdx.x; int b=bs>>6, s_=bs&63;
  const float* dt = bc2 + ((size_t)(b*192+128+s_))*LPIX;
  const float* Bm = bc2 + ((size_t)(b*192+s_))*LPIX;
  __shared__ float row[LPIX];
  __shared__ float red[256];
  int t=threadIdx.x;
  float mx=-1e30f;
  for(int l=t;l<LPIX;l+=256){ float v=dt[l]; row[l]=v; mx=fmaxf(mx,v); }
  red[t]=mx; __syncthreads();
  for(int o=128;o>0;o>>=1){ if(t<o) red[t]=fmaxf(red[t],red[t+o]); __syncthreads(); }
  mx=red[0]; __syncthreads();
  float sum=0;
  for(int l=t;l<LPIX;l+=256){ float e=__expf(row[l]-mx); row[l]=e; sum+=e; }
  red[t]=sum; __syncthreads();
  for(int o=128;o>0;o>>=1){ if(t<o) red[t]+=red[t+o]; __syncthreads(); }
  float inv=1.f/red[0];
  for(int l=t;l<LPIX;l+=256) wgt[((size_t)(b*S+s_))*LPIX+l] = row[l]*inv*Bm[l];
}

__global__ void k_h(const float* X, const float* wgt, float* h){
  int idx = blockIdx.x*256+threadIdx.x; if(idx>=B*C*S) return;
  int s_=idx%S, c=(idx/S)%C, b=idx/(S*C);
  const float* xp = X + ((size_t)(b*DIM+128+c))*LPIX;
  const float* wp = wgt + (size_t)(b*S+s_)*LPIX;
  float acc=0;
  for(int l=0;l<LPIX;l++) acc += xp[l]*wp[l];
  h[idx]=acc;
}

__global__ void k_mix(const float* h, const float* hzw, const float* Dp, float* g1){
  int idx = blockIdx.x*256+threadIdx.x; if(idx>=B*C*S) return;
  int s_=idx%S, c=(idx/S)%C, b=idx/(S*C);
  const float* hp = h + (size_t)b*C*S + s_;
  float hv=0, zv=0;
  for(int k=0;k<C;k++){ float x=hp[(size_t)k*S]; hv+=hzw[(size_t)c*C+k]*x; zv+=hzw[(size_t)(C+c)*C+k]*x; }
  float sil = zv/(1.f+__expf(-zv));
  g1[idx] = hv*sil + hv*Dp[0];
}

__global__ void k_ho(const float* g1, const float* outw, float* ho){
  int idx = blockIdx.x*256+threadIdx.x; if(idx>=B*C*S) return;
  int s_=idx%S, c=(idx/S)%C, b=idx/(S*C);
  float acc=0;
  for(int k=0;k<C;k++) acc += outw[(size_t)c*C+k]*g1[((size_t)(b*C+k))*S+s_];
  ho[idx]=acc;
}

__global__ void k_x3(const float* ho, const float* bc2, float* xa){
  int idx = blockIdx.x*256+threadIdx.x; if(idx>=B*C*LPIX) return;
  int l=idx%LPIX, c=(idx/LPIX)%C, b=idx/(LPIX*C);
  const float* hp = ho + (size_t)(b*C+c)*S;
  const float* cm = bc2 + ((size_t)(b*192+64))*LPIX + l;
  float acc=0;
  for(int s_=0;s_<S;s_++) acc += hp[s_]*cm[(size_t)s_*LPIX];
  xa[((size_t)(b*DIM+128+c))*LPIX + l] = acc;
}

// ---- branch 4 ----
__global__ void k_qkv(const float* X, const float* w, float* qkvb){
  int idx = blockIdx.x*256+threadIdx.x; if(idx>=B*48*LPIX) return;
  int l=idx%LPIX, og=(idx/LPIX)%48, b=idx/(LPIX*48);
  int o0=og*4;
  const float* xp = X + ((size_t)(b*DIM+192))*LPIX + l;
  float s[4]={0,0,0,0};
  for(int c=0;c<C;c++){ float xv=xp[(size_t)c*LPIX];
    for(int t=0;t<4;t++) s[t]+=w[(size_t)(o0+t)*C+c]*xv; }
  int which=o0>>6, rem=o0&63, head=rem>>2;
  float4* dst = (float4*)(qkvb + (size_t)which*B*NH*LPIX*HD + ((size_t)((b*NH+head)*LPIX+l))*HD);
  *dst = make_float4(s[0],s[1],s[2],s[3]);
}

// wave-per-row attention; no max-shift (|score| <= ~8 << 88, softmax shift-invariant)
__global__ void k_attn(const float* qkvb, float* obuf){
  int bh = blockIdx.x >> 3, seg = blockIdx.x & 7;
  int b = bh>>4, h = bh&15;
  const float4* q4 = (const float4*)(qkvb + (size_t)bh*LPIX*HD);
  const float4* k4 = (const float4*)(qkvb + (size_t)(B*NH + bh)*LPIX*HD);
  const float4* v4 = (const float4*)(qkvb + (size_t)(2*B*NH + bh)*LPIX*HD);
  __shared__ float4 ks[LPIX], vs[LPIX];
  for(int i=threadIdx.x;i<LPIX;i+=256){ ks[i]=k4[i]; vs[i]=v4[i]; }
  __syncthreads();
  int wave = threadIdx.x>>6, lane = threadIdx.x&63;
  int r0 = seg*98;
  for(int r=r0+wave; r<r0+98; r+=4){
    float4 qv = q4[r];
    float ls=0,a0=0,a1=0,a2=0,a3=0;
    for(int m=lane; m<LPIX; m+=64){
      float4 kv = ks[m];
      float sc = 0.5f*(qv.x*kv.x+qv.y*kv.y+qv.z*kv.z+qv.w*kv.w);
      float p = __expf(sc);
      float4 vv = vs[m];
      ls+=p; a0+=p*vv.x; a1+=p*vv.y; a2+=p*vv.z; a3+=p*vv.w;
    }
    for(int off=32; off; off>>=1){
      ls += __shfl_xor(ls,off);
      a0 += __shfl_xor(a0,off); a1 += __shfl_xor(a1,off);
      a2 += __shfl_xor(a2,off); a3 += __shfl_xor(a3,off);
    }
    if(lane==0){
      float inv = 1.f/ls;
      float* op = obuf + ((size_t)(b*LPIX+r))*C + h*4;
      op[0]=a0*inv; op[1]=a1*inv; op[2]=a2*inv; op[3]=a3*inv;
    }
  }
}

__global__ void k_x4(const float* X, const float* obuf, const float* projw, const float* bnp, float* xa){
  int idx = blockIdx.x*256+threadIdx.x; if(idx>=B*(C/4)*LPIX) return;
  int l=idx%LPIX, cg=(idx/LPIX)%(C/4), b=idx/(LPIX*(C/4));
  int c0=cg*4;
  const float* op = obuf + ((size_t)(b*LPIX+l))*C;
  float s[4]={0,0,0,0};
  for(int k=0;k<C;k++){ float ov=op[k];
    for(int t=0;t<4;t++) s[t]+=projw[(size_t)(c0+t)*C+k]*ov; }
  for(int t=0;t<4;t++){
    float v = s[t] + X[((size_t)(b*DIM+192+c0+t))*LPIX + l];
    xa[((size_t)(b*DIM+192+c0+t))*LPIX + l] = bnorm(v,bnp,c0+t,C);
  }
}

// ---- merge MLP ----
__global__ void k_mid(const float* xa, const float* m1w, const float* bnp, float* mid){
  int idx = blockIdx.x*256+threadIdx.x; if(idx>=B*(HID/4)*LPIX) return;
  int l=idx%LPIX, jg=(idx/LPIX)%(HID/4), b=idx/(LPIX*(HID/4));
  int j0=jg*4;
  const float* xp = xa + (size_t)b*DIM*LPIX + l;
  float s[4]={0,0,0,0};
  for(int c=0;c<DIM;c++){ float xv=xp[(size_t)c*LPIX];
    for(int t=0;t<4;t++) s[t]+=m1w[(size_t)(j0+t)*DIM+c]*xv; }
  for(int t=0;t<4;t++)
    mid[((size_t)(b*HID+j0+t))*LPIX + l] = fmaxf(bnorm(s[t],bnp,j0+t,HID),0.f);
}

__global__ void k_out(const float* X, const float* mid, const float* m2w, const float* bnp, float* out){
  int idx = blockIdx.x*256+threadIdx.x; if(idx>=B*(DIM/4)*LPIX) return;
  int l=idx%LPIX, cg=(idx/LPIX)%(DIM/4), b=idx/(LPIX*(DIM/4));
  int c0=cg*4;
  const float* mp_ = mid + (size_t)b*HID*LPIX + l;
  float s[4]={0,0,0,0};
  for(int j=0;j<HID;j++){ float mv=mp_[(size_t)j*LPIX];
    for(int t=0;t<4;t++) s[t]+=m2w[(size_t)(c0+t)*HID+j]*mv; }
  for(int t=0;t<4;t++){
    size_t oi = ((size_t)(b*DIM+c0+t))*LPIX + l;
    out[oi] = bnorm(s[t],bnp,c0+t,DIM) + X[oi];
  }
}

extern "C" void kernel_launch(void* const* d_in, const int* in_sizes, int n_in,
                              void* d_out, int out_size, void* d_ws, size_t ws_size,
                              hipStream_t stream) {
  const float* X      = (const float*)d_in[0];
  const float* dw1_w  = (const float*)d_in[1];
  const float* dw1_b  = (const float*)d_in[2];
  const float* bn_dw1 = (const float*)d_in[3];
  const float* f1_w   = (const float*)d_in[4];
  const float* f1_b   = (const float*)d_in[5];
  const float* f2_w   = (const float*)d_in[6];
  const float* f2_b   = (const float*)d_in[7];
  const float* g_w    = (const float*)d_in[8];
  const float* g_b    = (const float*)d_in[9];
  const float* bn_g   = (const float*)d_in[10];
  const float* dw2_w  = (const float*)d_in[11];
  const float* dw2_b  = (const float*)d_in[12];
  const float* hatt1w = (const float*)d_in[13];
  const float* vatt1w = (const float*)d_in[14];
  const float* hatt2w = (const float*)d_in[15];
  const float* vatt2w = (const float*)d_in[16];
  const float* bn_mra = (const float*)d_in[17];
  const float* bcdt_w = (const float*)d_in[18];
  const float* ssd_dw = (const float*)d_in[19];
  const float* hz_w   = (const float*)d_in[20];
  const float* out_w  = (const float*)d_in[21];
  const float* D_p    = (const float*)d_in[23];
  const float* qkv_w  = (const float*)d_in[24];
  const float* proj_w = (const float*)d_in[25];
  const float* bn_n4  = (const float*)d_in[26];
  const float* mlp1_w = (const float*)d_in[27];
  const float* bn_mlp = (const float*)d_in[28];
  const float* mlp2_w = (const float*)d_in[29];
  const float* bn_n1  = (const float*)d_in[30];

  float* ws   = (float*)d_ws;
  float* x1o  = ws+OFF_X1O;  float* t1  = ws+OFF_T1;  float* t2  = ws+OFF_T2;
  float* xa   = ws+OFF_XA;   float* mpb = ws+OFF_MP;  float* xt  = ws+OFF_XT;
  float* att  = ws+OFF_ATT;  float* bc1 = ws+OFF_BC1; float* bc2 = ws+OFF_BC2;
  float* wgt  = ws+OFF_WGT;  float* hbuf= ws+OFF_H;   float* g1  = ws+OFF_G1;
  float* ho   = ws+OFF_HO;   float* qkvb= ws+OFF_QKV; float* obuf= ws+OFF_O;
  float* mid  = ws+OFF_MID;

  dim3 blk(256);
  #define NB(n) dim3((unsigned)(((n)+255)/256))
  const int NCL = B*C*LPIX;

  // branch 1
  k_dw1  <<<NB(NCL),blk,0,stream>>>(X,dw1_w,dw1_b,bn_dw1,x1o);
  k_star <<<NB(B*(HID/4)*LPIX),blk,0,stream>>>(x1o,f1_w,f1_b,f2_w,f2_b,t1);
  k_gproj<<<NB(B*(C/4)*LPIX),blk,0,stream>>>(t1,g_w,g_b,bn_g,t2);
  k_dw2  <<<NB(NCL),blk,0,stream>>>(t2,dw2_w,dw2_b,xa);
  // branch 2
  k_mp   <<<NB(NCL),blk,0,stream>>>(X,mpb);
  k_blur <<<NB(B*C*100),blk,0,stream>>>(mpb,xt);
  k_mra  <<<NB(B*C*100),blk,0,stream>>>(xt,hatt1w,vatt1w,hatt2w,vatt2w,bn_mra,att);
  k_x2   <<<NB(NCL),blk,0,stream>>>(X,att,xa);
  // branch 3
  k_bcdt <<<NB(B*48*LPIX),blk,0,stream>>>(X,bcdt_w,bc1);
  k_ssddw<<<NB(B*192*LPIX),blk,0,stream>>>(bc1,ssd_dw,bc2);
  k_ssd_softmax<<<dim3(B*S),blk,0,stream>>>(bc2,wgt);
  k_h    <<<NB(B*C*S),blk,0,stream>>>(X,wgt,hbuf);
  k_mix  <<<NB(B*C*S),blk,0,stream>>>(hbuf,hz_w,D_p,g1);
  k_ho   <<<NB(B*C*S),blk,0,stream>>>(g1,out_w,ho);
  k_x3   <<<NB(NCL),blk,0,stream>>>(ho,bc2,xa);
  // branch 4
  k_qkv  <<<NB(B*48*LPIX),blk,0,stream>>>(X,qkv_w,qkvb);
  k_attn <<<dim3(B*NH*8),blk,0,stream>>>(qkvb,obuf);
  k_x4   <<<NB(B*(C/4)*LPIX),blk,0,stream>>>(X,obuf,proj_w,bn_n4,xa);
  // merge MLP
  k_mid  <<<NB(B*(HID/4)*LPIX),blk,0,stream>>>(xa,mlp1_w,bn_mlp,mid);
  k_out  <<<NB(B*(DIM/4)*LPIX),blk,0,stream>>>(X,mid,mlp2_w,bn_n1,(float*)d_out);
  #undef NB
}